// Round 6
// baseline (789.745 us; speedup 1.0000x reference)
//
#include <hip/hip_runtime.h>

typedef __bf16 bf16;
typedef __bf16 bf16x8 __attribute__((ext_vector_type(8)));
typedef __bf16 bf16x4 __attribute__((ext_vector_type(4)));
typedef float  floatx4 __attribute__((ext_vector_type(4)));

#define B_ 4
#define T_ 2048
#define E_ 1024
#define H_ 16
#define D_ 64
#define NTE_ (B_ * T_ * E_)  // 8388608 elems

#define NEG_BIG (-1e30f)

// ---- static device memory ------------------------------------------------
// bf16 staging for fp32 inputs that feed MFMA: q,k,v + Wq,Wk,Wv,Wo.
// (biases, cos, sin stay fp32, read directly by consumers.)
#define OFF_CQ 0ull
#define OFF_CK ((unsigned long long)NTE_)
#define OFF_CV (2ull * NTE_)
#define OFF_WQ (3ull * NTE_)
#define OFF_WK (OFF_WQ + 1048576ull)
#define OFF_WV (OFF_WK + 1048576ull)
#define OFF_WO (OFF_WV + 1048576ull)
__device__ bf16 g_conv[3ull * NTE_ + 4ull * 1048576ull];
// Pipeline scratch: qp | kp | vp | vt | op
__device__ bf16 g_scratch[5ull * NTE_];

__device__ __forceinline__ floatx4 mfma16(bf16x8 a, bf16x8 b, floatx4 c) {
  return __builtin_amdgcn_mfma_f32_16x16x32_bf16(a, b, c, 0, 0, 0);
}

// async global->LDS, 16B per lane. LDS dest = wave-uniform base + lane*16.
__device__ __forceinline__ void async_copy16(void* lds, const void* g) {
  __builtin_amdgcn_global_load_lds(
      (const __attribute__((address_space(1))) unsigned int*)g,
      (__attribute__((address_space(3))) unsigned int*)lds, 16, 0, 0);
}

// ---------------------------------------------------------------------------
// One fused fp32->bf16 convert for the 7 MFMA-feeding tensors (was 13
// launches; tiny launches were ~5-10us of gap each).
// ---------------------------------------------------------------------------
__global__ __launch_bounds__(256) void convert_all(const float4* __restrict__ q,
                                                   const float4* __restrict__ k,
                                                   const float4* __restrict__ v,
                                                   const float4* __restrict__ wq,
                                                   const float4* __restrict__ wk,
                                                   const float4* __restrict__ wv,
                                                   const float4* __restrict__ wo) {
  const float4* srcs[7] = {q, k, v, wq, wk, wv, wo};
  bf16x4* dsts[7] = {(bf16x4*)(g_conv + OFF_CQ), (bf16x4*)(g_conv + OFF_CK),
                     (bf16x4*)(g_conv + OFF_CV), (bf16x4*)(g_conv + OFF_WQ),
                     (bf16x4*)(g_conv + OFF_WK), (bf16x4*)(g_conv + OFF_WV),
                     (bf16x4*)(g_conv + OFF_WO)};
  const int n4s[7] = {NTE_ / 4, NTE_ / 4, NTE_ / 4, 262144, 262144, 262144, 262144};
  int i0 = blockIdx.x * 256 + threadIdx.x;
  int stride = gridDim.x * 256;
#pragma unroll
  for (int s = 0; s < 7; ++s) {
    const float4* sp = srcs[s];
    bf16x4* dp = dsts[s];
    int n4 = n4s[s];
    for (int i = i0; i < n4; i += stride) {
      float4 vv = sp[i];
      bf16x4 o;
      o[0] = (bf16)vv.x; o[1] = (bf16)vv.y; o[2] = (bf16)vv.z; o[3] = (bf16)vv.w;
      dp[i] = o;
    }
  }
}

// ---------------------------------------------------------------------------
// GEMM: Y = X @ W^T + bias(fp32).  128x128 tile, 4 waves (2x2 of 64x64),
// BK=32, global_load_lds width-16 staging (m97 pattern).
// A-frag: A[m=lane&15][k=(lane>>4)*8+j]; B-frag: W[n=lane&15][k=...]
// C/D:    col(n)=lane&15, row(m)=(lane>>4)*4+reg   (m89/m91-verified)
// ---------------------------------------------------------------------------
template <typename OUT_T>
__global__ __launch_bounds__(256) void gemm_bt(const bf16* __restrict__ X,
                                               const bf16* __restrict__ W,
                                               const float* __restrict__ bias,
                                               OUT_T* __restrict__ Y) {
  constexpr int K = 1024, N = 1024;
  __shared__ bf16 sA[128 * 32];
  __shared__ bf16 sB[128 * 32];
  const int tid = threadIdx.x;
  const int w = tid >> 6;
  const int l = tid & 63;
  const int q = l >> 4;
  const int r = l & 15;
  const int M0 = blockIdx.x * 128;
  const int N0 = blockIdx.y * 128;
  const int wm = (w >> 1) * 64, wn = (w & 1) * 64;

  floatx4 acc[4][4];
  for (int mi = 0; mi < 4; ++mi)
    for (int ni = 0; ni < 4; ++ni) acc[mi][ni] = (floatx4){0.f, 0.f, 0.f, 0.f};

  for (int k0 = 0; k0 < K; k0 += 32) {
    __syncthreads();
#pragma unroll
    for (int i = 0; i < 2; ++i) {
      int idx = i * 256 + tid;
      int row = idx >> 2, cc = (idx & 3) << 3;
      // LDS dest: wave-uniform base + lane*16B (row*32+cc is lane-linear)
      bf16* dA = sA + (i * 2048 + w * 512);
      async_copy16(dA, X + (size_t)(M0 + row) * K + k0 + cc);
      bf16* dB = sB + (i * 2048 + w * 512);
      async_copy16(dB, W + (size_t)(N0 + row) * K + k0 + cc);
    }
    __syncthreads();

    bf16x8 a[4], b[4];
#pragma unroll
    for (int mi = 0; mi < 4; ++mi)
      a[mi] = *(const bf16x8*)(sA + (wm + mi * 16 + r) * 32 + q * 8);
#pragma unroll
    for (int ni = 0; ni < 4; ++ni)
      b[ni] = *(const bf16x8*)(sB + (wn + ni * 16 + r) * 32 + q * 8);
#pragma unroll
    for (int mi = 0; mi < 4; ++mi)
#pragma unroll
      for (int ni = 0; ni < 4; ++ni) acc[mi][ni] = mfma16(a[mi], b[ni], acc[mi][ni]);
  }

#pragma unroll
  for (int mi = 0; mi < 4; ++mi) {
    int rowbase = M0 + wm + mi * 16 + q * 4;
#pragma unroll
    for (int ni = 0; ni < 4; ++ni) {
      int col = N0 + wn + ni * 16 + r;
      float bv = bias[col];
#pragma unroll
      for (int rr = 0; rr < 4; ++rr) {
        Y[(size_t)(rowbase + rr) * N + col] = (OUT_T)(acc[mi][ni][rr] + bv);
      }
    }
  }
}

// ---------------------------------------------------------------------------
// RMSNorm + RoPE in place on qp,kp. 16-lane group per (b,t,h) row of 64.
// cos/sin read directly as fp32.
// ---------------------------------------------------------------------------
__global__ __launch_bounds__(256) void rmsnorm_rope(const float* __restrict__ cosb,
                                                    const float* __restrict__ sinb) {
  bf16* qp = g_scratch;
  bf16* kp = g_scratch + (unsigned long long)NTE_;
  constexpr int HR = B_ * T_ * H_;
  int gid = blockIdx.x * 16 + (threadIdx.x >> 4);
  int j = threadIdx.x & 15;
  bf16* base = (gid < HR) ? qp : kp;
  int row = gid & (HR - 1);
  int t = (row >> 4) & (T_ - 1);
  bf16* p = base + (size_t)row * 64 + j * 4;

  bf16x4 xv = *(const bf16x4*)p;
  float x[4], ss = 0.f;
#pragma unroll
  for (int i = 0; i < 4; ++i) { x[i] = (float)xv[i]; ss += x[i] * x[i]; }
#pragma unroll
  for (int m = 1; m < 16; m <<= 1) ss += __shfl_xor(ss, m, 64);
  float rs = rsqrtf(ss * (1.0f / 64.0f) + 1e-6f);

  float y[4], pr[4];
#pragma unroll
  for (int i = 0; i < 4; ++i) y[i] = x[i] * rs;
#pragma unroll
  for (int i = 0; i < 4; ++i) pr[i] = __shfl_xor(y[i], 8, 64);

  int dbase = (j & 7) * 4;
  bf16x4 ov;
#pragma unroll
  for (int i = 0; i < 4; ++i) {
    float c = cosb[t * 32 + dbase + i];
    float s = sinb[t * 32 + dbase + i];
    float o = (j < 8) ? (y[i] * c - pr[i] * s) : (y[i] * c + pr[i] * s);
    ov[i] = (bf16)o;
  }
  *(bf16x4*)p = ov;
}

// ---------------------------------------------------------------------------
// Transpose V: vp (b,t,h,d) -> vt (b,h,d,t).
// ---------------------------------------------------------------------------
__global__ __launch_bounds__(256) void transpose_v() {
  const bf16* vp = g_scratch + 2ull * NTE_;
  bf16* vt = g_scratch + 3ull * NTE_;
  __shared__ bf16 tile[64][72];
  int bid = blockIdx.x;
  int tt = bid & 31;
  int bh = bid >> 5;
  int h = bh & 15, b = bh >> 4;
  int t0 = tt * 64;
  int tid = threadIdx.x;
#pragma unroll
  for (int i = 0; i < 2; ++i) {
    int idx = i * 256 + tid;
    int row = idx >> 3, cc = (idx & 7) * 8;
    bf16x8 v = *(const bf16x8*)(vp + (size_t)(b * T_ + t0 + row) * E_ + h * D_ + cc);
#pragma unroll
    for (int jj = 0; jj < 8; ++jj) tile[row][cc + jj] = v[jj];
  }
  __syncthreads();
#pragma unroll
  for (int i = 0; i < 2; ++i) {
    int idx = i * 256 + tid;
    int d = idx >> 3, tc = (idx & 7) * 8;
    bf16x8 v;
#pragma unroll
    for (int jj = 0; jj < 8; ++jj) v[jj] = tile[tc + jj][d];
    *(bf16x8*)(vt + ((size_t)bh * D_ + d) * T_ + t0 + tc) = v;
  }
}

// ---------------------------------------------------------------------------
// Flash attention, causal — BARRIER-FREE. 4 independent waves per block,
// each owning 16 Q rows. K and V fragments load directly from global
// (coalesced 16B/lane, L1/L2-served; no sK/sV staging, no __syncthreads).
// LDS holds only the wave-private P strip, stride 88 (=176B, 16B-aligned;
// b128 read pattern (3r+q)%8 covers all 8 bank-groups -> conflict-free).
// ---------------------------------------------------------------------------
#define PSTR 88
__global__ __launch_bounds__(256) void flash_attn() {
  const bf16* qp = g_scratch;
  const bf16* kp = g_scratch + (unsigned long long)NTE_;
  const bf16* vt = g_scratch + 3ull * NTE_;
  bf16* op = g_scratch + 4ull * NTE_;

  __shared__ bf16 sP[4 * 16 * PSTR];

  int bid = blockIdx.x;
  int qt = bid & 31;
  int bh = bid >> 5;
  int h = bh & 15, b = bh >> 4;
  int Q0 = qt * 64;
  int tid = threadIdx.x, w = tid >> 6, l = tid & 63, q = l >> 4, r = l & 15;

  const bf16* kbase = kp + (size_t)(b * T_) * E_ + h * D_;
  const bf16* vbase = vt + (size_t)bh * D_ * T_;

  int qrow = Q0 + w * 16 + r;
  const bf16* qbase = qp + (size_t)(b * T_ + qrow) * E_ + h * D_;
  bf16x8 qa[2];
  qa[0] = *(const bf16x8*)(qbase + q * 8);
  qa[1] = *(const bf16x8*)(qbase + 32 + q * 8);

  float m_i[4], l_i[4];
  floatx4 o_acc[4];
#pragma unroll
  for (int i = 0; i < 4; ++i) {
    m_i[i] = NEG_BIG;
    l_i[i] = 0.f;
    o_acc[i] = (floatx4){0.f, 0.f, 0.f, 0.f};
  }

  bf16* pw = sP + w * (16 * PSTR);

  for (int kt0 = 0; kt0 <= Q0; kt0 += 64) {
    // S = Q K^T, K frags direct from global: K[key=sc*16+r][d=kk*32+q*8+j]
    floatx4 s[4];
#pragma unroll
    for (int sc = 0; sc < 4; ++sc) {
      const bf16* krow = kbase + (size_t)(kt0 + sc * 16 + r) * E_;
      bf16x8 kb0 = *(const bf16x8*)(krow + q * 8);
      bf16x8 kb1 = *(const bf16x8*)(krow + 32 + q * 8);
      floatx4 a = (floatx4){0.f, 0.f, 0.f, 0.f};
      a = mfma16(qa[0], kb0, a);
      a = mfma16(qa[1], kb1, a);
      s[sc] = a;
    }

    float rowmax[4] = {NEG_BIG, NEG_BIG, NEG_BIG, NEG_BIG};
#pragma unroll
    for (int sc = 0; sc < 4; ++sc) {
      int kglob = kt0 + sc * 16 + r;
#pragma unroll
      for (int rr = 0; rr < 4; ++rr) {
        int qglob = Q0 + w * 16 + q * 4 + rr;
        float v = fminf(s[sc][rr] * 0.125f, 1e30f);
        v = (kglob <= qglob) ? v : NEG_BIG;
        s[sc][rr] = v;
        rowmax[rr] = fmaxf(rowmax[rr], v);
      }
    }
#pragma unroll
    for (int rr = 0; rr < 4; ++rr)
#pragma unroll
      for (int m = 1; m < 16; m <<= 1)
        rowmax[rr] = fmaxf(rowmax[rr], __shfl_xor(rowmax[rr], m, 64));

    float alpha[4];
#pragma unroll
    for (int rr = 0; rr < 4; ++rr) {
      float mnew = fmaxf(m_i[rr], rowmax[rr]);
      alpha[rr] = __expf(m_i[rr] - mnew);
      m_i[rr] = mnew;
    }

    float rowsum[4] = {0.f, 0.f, 0.f, 0.f};
#pragma unroll
    for (int sc = 0; sc < 4; ++sc)
#pragma unroll
      for (int rr = 0; rr < 4; ++rr) {
        float p = __expf(s[sc][rr] - m_i[rr]);
        s[sc][rr] = p;
        rowsum[rr] += p;
      }
#pragma unroll
    for (int rr = 0; rr < 4; ++rr)
#pragma unroll
      for (int m = 1; m < 16; m <<= 1) rowsum[rr] += __shfl_xor(rowsum[rr], m, 64);
#pragma unroll
    for (int rr = 0; rr < 4; ++rr) l_i[rr] = l_i[rr] * alpha[rr] + rowsum[rr];

    // P: C-layout -> wave-private LDS (row-major [q_local][key], stride 88)
#pragma unroll
    for (int sc = 0; sc < 4; ++sc)
#pragma unroll
      for (int rr = 0; rr < 4; ++rr)
        pw[(q * 4 + rr) * PSTR + sc * 16 + r] = (bf16)s[sc][rr];
    asm volatile("s_waitcnt lgkmcnt(0)" ::: "memory");

#pragma unroll
    for (int dt = 0; dt < 4; ++dt)
#pragma unroll
      for (int rr = 0; rr < 4; ++rr) o_acc[dt][rr] *= alpha[rr];

    // O += P V : A = P[m=q_local][k=key] from LDS; B = V^T[n=d][k=key]
    // direct from global vt (b,h,d,t).
#pragma unroll
    for (int kk = 0; kk < 2; ++kk) {
      bf16x8 pa = *(const bf16x8*)(pw + r * PSTR + kk * 32 + q * 8);
#pragma unroll
      for (int dt = 0; dt < 4; ++dt) {
        bf16x8 vb = *(const bf16x8*)(vbase + (size_t)(dt * 16 + r) * T_ + kt0 +
                                     kk * 32 + q * 8);
        o_acc[dt] = mfma16(pa, vb, o_acc[dt]);
      }
    }
  }

#pragma unroll
  for (int dt = 0; dt < 4; ++dt)
#pragma unroll
    for (int rr = 0; rr < 4; ++rr) {
      int t = Q0 + w * 16 + q * 4 + rr;
      float oo = o_acc[dt][rr] / l_i[rr];  // l_i >= 1 (diagonal term)
      op[(size_t)(b * T_ + t) * E_ + h * D_ + dt * 16 + r] = (bf16)oo;
    }
}

// ---------------------------------------------------------------------------
extern "C" void kernel_launch(void* const* d_in, const int* in_sizes, int n_in,
                              void* d_out, int out_size, void* d_ws, size_t ws_size,
                              hipStream_t stream) {
  float* out = (float*)d_out;  // fp32 output, per reference

  void* cvp_ = nullptr;
  void* sp_ = nullptr;
  hipGetSymbolAddress(&cvp_, HIP_SYMBOL(g_conv));
  hipGetSymbolAddress(&sp_, HIP_SYMBOL(g_scratch));
  bf16* cv = (bf16*)cvp_;
  bf16* sc = (bf16*)sp_;

  const float* cosb = (const float*)d_in[4];
  const float* sinb = (const float*)d_in[5];
  const float* bq = (const float*)d_in[7];
  const float* bk = (const float*)d_in[9];
  const float* bv = (const float*)d_in[11];
  const float* bo = (const float*)d_in[13];

  convert_all<<<dim3(1024), dim3(256), 0, stream>>>(
      (const float4*)d_in[0], (const float4*)d_in[1], (const float4*)d_in[2],
      (const float4*)d_in[6], (const float4*)d_in[8], (const float4*)d_in[10],
      (const float4*)d_in[12]);

  bf16* qp = sc;
  bf16* kp = sc + 1ull * NTE_;
  bf16* vp = sc + 2ull * NTE_;
  bf16* op = sc + 4ull * NTE_;

  dim3 gg(64, 8), bb(256);
  gemm_bt<bf16><<<gg, bb, 0, stream>>>(cv + OFF_CQ, cv + OFF_WQ, bq, qp);
  gemm_bt<bf16><<<gg, bb, 0, stream>>>(cv + OFF_CK, cv + OFF_WK, bk, kp);
  gemm_bt<bf16><<<gg, bb, 0, stream>>>(cv + OFF_CV, cv + OFF_WV, bv, vp);
  rmsnorm_rope<<<dim3(16384), bb, 0, stream>>>(cosb, sinb);
  transpose_v<<<dim3(2048), bb, 0, stream>>>();
  flash_attn<<<dim3(2048), bb, 0, stream>>>();
  gemm_bt<float><<<gg, bb, 0, stream>>>(op, cv + OFF_WO, bo, out);
}

// Round 7
// 483.346 us; speedup vs baseline: 1.6339x; 1.6339x over previous
//
#include <hip/hip_runtime.h>

typedef __bf16 bf16;
typedef __bf16 bf16x8 __attribute__((ext_vector_type(8)));
typedef __bf16 bf16x4 __attribute__((ext_vector_type(4)));
typedef float  floatx4 __attribute__((ext_vector_type(4)));

#define B_ 4
#define T_ 2048
#define E_ 1024
#define H_ 16
#define D_ 64
#define NTE_ (B_ * T_ * E_)  // 8388608 elems

#define NEG_BIG (-1e30f)

// ---- static device memory ------------------------------------------------
#define OFF_CQ 0ull
#define OFF_CK ((unsigned long long)NTE_)
#define OFF_CV (2ull * NTE_)
#define OFF_WQ (3ull * NTE_)
#define OFF_WK (OFF_WQ + 1048576ull)
#define OFF_WV (OFF_WK + 1048576ull)
#define OFF_WO (OFF_WV + 1048576ull)
__device__ bf16 g_conv[3ull * NTE_ + 4ull * 1048576ull];
// Pipeline scratch: qp | kp | vp | vt | op
__device__ bf16 g_scratch[5ull * NTE_];

__device__ __forceinline__ floatx4 mfma16(bf16x8 a, bf16x8 b, floatx4 c) {
  return __builtin_amdgcn_mfma_f32_16x16x32_bf16(a, b, c, 0, 0, 0);
}

__device__ __forceinline__ void async_copy16(void* lds, const void* g) {
  __builtin_amdgcn_global_load_lds(
      (const __attribute__((address_space(1))) unsigned int*)g,
      (__attribute__((address_space(3))) unsigned int*)lds, 16, 0, 0);
}

// ---------------------------------------------------------------------------
// One fused fp32->bf16 convert for the 7 MFMA-feeding tensors.
// ---------------------------------------------------------------------------
__global__ __launch_bounds__(256) void convert_all(const float4* __restrict__ q,
                                                   const float4* __restrict__ k,
                                                   const float4* __restrict__ v,
                                                   const float4* __restrict__ wq,
                                                   const float4* __restrict__ wk,
                                                   const float4* __restrict__ wv,
                                                   const float4* __restrict__ wo) {
  const float4* srcs[7] = {q, k, v, wq, wk, wv, wo};
  bf16x4* dsts[7] = {(bf16x4*)(g_conv + OFF_CQ), (bf16x4*)(g_conv + OFF_CK),
                     (bf16x4*)(g_conv + OFF_CV), (bf16x4*)(g_conv + OFF_WQ),
                     (bf16x4*)(g_conv + OFF_WK), (bf16x4*)(g_conv + OFF_WV),
                     (bf16x4*)(g_conv + OFF_WO)};
  const int n4s[7] = {NTE_ / 4, NTE_ / 4, NTE_ / 4, 262144, 262144, 262144, 262144};
  int i0 = blockIdx.x * 256 + threadIdx.x;
  int stride = gridDim.x * 256;
#pragma unroll
  for (int s = 0; s < 7; ++s) {
    const float4* sp = srcs[s];
    bf16x4* dp = dsts[s];
    int n4 = n4s[s];
    for (int i = i0; i < n4; i += stride) {
      float4 vv = sp[i];
      bf16x4 o;
      o[0] = (bf16)vv.x; o[1] = (bf16)vv.y; o[2] = (bf16)vv.z; o[3] = (bf16)vv.w;
      dp[i] = o;
    }
  }
}

// ---------------------------------------------------------------------------
// GEMM: Y = X @ W^T + bias(fp32).  128x128 tile, 4 waves (2x2 of 64x64),
// BK=32, global_load_lds width-16 staging (m97 pattern).
// ---------------------------------------------------------------------------
template <typename OUT_T>
__global__ __launch_bounds__(256) void gemm_bt(const bf16* __restrict__ X,
                                               const bf16* __restrict__ W,
                                               const float* __restrict__ bias,
                                               OUT_T* __restrict__ Y) {
  constexpr int K = 1024, N = 1024;
  __shared__ bf16 sA[128 * 32];
  __shared__ bf16 sB[128 * 32];
  const int tid = threadIdx.x;
  const int w = tid >> 6;
  const int l = tid & 63;
  const int q = l >> 4;
  const int r = l & 15;
  const int M0 = blockIdx.x * 128;
  const int N0 = blockIdx.y * 128;
  const int wm = (w >> 1) * 64, wn = (w & 1) * 64;

  floatx4 acc[4][4];
  for (int mi = 0; mi < 4; ++mi)
    for (int ni = 0; ni < 4; ++ni) acc[mi][ni] = (floatx4){0.f, 0.f, 0.f, 0.f};

  for (int k0 = 0; k0 < K; k0 += 32) {
    __syncthreads();
#pragma unroll
    for (int i = 0; i < 2; ++i) {
      int idx = i * 256 + tid;
      int row = idx >> 2, cc = (idx & 3) << 3;
      bf16* dA = sA + (i * 2048 + w * 512);
      async_copy16(dA, X + (size_t)(M0 + row) * K + k0 + cc);
      bf16* dB = sB + (i * 2048 + w * 512);
      async_copy16(dB, W + (size_t)(N0 + row) * K + k0 + cc);
    }
    __syncthreads();

    bf16x8 a[4], b[4];
#pragma unroll
    for (int mi = 0; mi < 4; ++mi)
      a[mi] = *(const bf16x8*)(sA + (wm + mi * 16 + r) * 32 + q * 8);
#pragma unroll
    for (int ni = 0; ni < 4; ++ni)
      b[ni] = *(const bf16x8*)(sB + (wn + ni * 16 + r) * 32 + q * 8);
#pragma unroll
    for (int mi = 0; mi < 4; ++mi)
#pragma unroll
      for (int ni = 0; ni < 4; ++ni) acc[mi][ni] = mfma16(a[mi], b[ni], acc[mi][ni]);
  }

#pragma unroll
  for (int mi = 0; mi < 4; ++mi) {
    int rowbase = M0 + wm + mi * 16 + q * 4;
#pragma unroll
    for (int ni = 0; ni < 4; ++ni) {
      int col = N0 + wn + ni * 16 + r;
      float bv = bias[col];
#pragma unroll
      for (int rr = 0; rr < 4; ++rr) {
        Y[(size_t)(rowbase + rr) * N + col] = (OUT_T)(acc[mi][ni][rr] + bv);
      }
    }
  }
}

// ---------------------------------------------------------------------------
// RMSNorm + RoPE in place on qp,kp.
// ---------------------------------------------------------------------------
__global__ __launch_bounds__(256) void rmsnorm_rope(const float* __restrict__ cosb,
                                                    const float* __restrict__ sinb) {
  bf16* qp = g_scratch;
  bf16* kp = g_scratch + (unsigned long long)NTE_;
  constexpr int HR = B_ * T_ * H_;
  int gid = blockIdx.x * 16 + (threadIdx.x >> 4);
  int j = threadIdx.x & 15;
  bf16* base = (gid < HR) ? qp : kp;
  int row = gid & (HR - 1);
  int t = (row >> 4) & (T_ - 1);
  bf16* p = base + (size_t)row * 64 + j * 4;

  bf16x4 xv = *(const bf16x4*)p;
  float x[4], ss = 0.f;
#pragma unroll
  for (int i = 0; i < 4; ++i) { x[i] = (float)xv[i]; ss += x[i] * x[i]; }
#pragma unroll
  for (int m = 1; m < 16; m <<= 1) ss += __shfl_xor(ss, m, 64);
  float rs = rsqrtf(ss * (1.0f / 64.0f) + 1e-6f);

  float y[4], pr[4];
#pragma unroll
  for (int i = 0; i < 4; ++i) y[i] = x[i] * rs;
#pragma unroll
  for (int i = 0; i < 4; ++i) pr[i] = __shfl_xor(y[i], 8, 64);

  int dbase = (j & 7) * 4;
  bf16x4 ov;
#pragma unroll
  for (int i = 0; i < 4; ++i) {
    float c = cosb[t * 32 + dbase + i];
    float s = sinb[t * 32 + dbase + i];
    float o = (j < 8) ? (y[i] * c - pr[i] * s) : (y[i] * c + pr[i] * s);
    ov[i] = (bf16)o;
  }
  *(bf16x4*)p = ov;
}

// ---------------------------------------------------------------------------
// Transpose V: vp (b,t,h,d) -> vt (b,h,d,t).
// ---------------------------------------------------------------------------
__global__ __launch_bounds__(256) void transpose_v() {
  const bf16* vp = g_scratch + 2ull * NTE_;
  bf16* vt = g_scratch + 3ull * NTE_;
  __shared__ bf16 tile[64][72];
  int bid = blockIdx.x;
  int tt = bid & 31;
  int bh = bid >> 5;
  int h = bh & 15, b = bh >> 4;
  int t0 = tt * 64;
  int tid = threadIdx.x;
#pragma unroll
  for (int i = 0; i < 2; ++i) {
    int idx = i * 256 + tid;
    int row = idx >> 3, cc = (idx & 7) * 8;
    bf16x8 v = *(const bf16x8*)(vp + (size_t)(b * T_ + t0 + row) * E_ + h * D_ + cc);
#pragma unroll
    for (int jj = 0; jj < 8; ++jj) tile[row][cc + jj] = v[jj];
  }
  __syncthreads();
#pragma unroll
  for (int i = 0; i < 2; ++i) {
    int idx = i * 256 + tid;
    int d = idx >> 3, tc = (idx & 7) * 8;
    bf16x8 v;
#pragma unroll
    for (int jj = 0; jj < 8; ++jj) v[jj] = tile[tc + jj][d];
    *(bf16x8*)(vt + ((size_t)bh * D_ + d) * T_ + t0 + tc) = v;
  }
}

// ---------------------------------------------------------------------------
// Flash attention, causal. LDS-staged K/V (coalesced global loads, shared
// across 4 waves), register double-buffered prefetch, padded LDS strides
// (KSTR=72 kills the 16-way fragment-read conflict; PSTR=68 drops P-writes
// to 2-way). Mask applied ONLY on the diagonal tile (provably sufficient).
// Block j handles Q-strips j and 31-j: exactly 33 tile-iters per block.
// ---------------------------------------------------------------------------
#define KSTR 72
#define PSTR 68
__global__ __launch_bounds__(256) void flash_attn() {
  const bf16* qp = g_scratch;
  const bf16* kp = g_scratch + (unsigned long long)NTE_;
  const bf16* vt = g_scratch + 3ull * NTE_;
  bf16* op = g_scratch + 4ull * NTE_;

  __shared__ bf16 sK[64 * KSTR];
  __shared__ bf16 sV[64 * KSTR];     // [d][key]
  __shared__ bf16 sP[4 * 16 * PSTR]; // wave-private strips

  int bid = blockIdx.x;
  int pairIdx = bid & 15;
  int bh = bid >> 4;
  int h = bh & 15, b = bh >> 4;
  int tid = threadIdx.x, w = tid >> 6, l = tid & 63, q = l >> 4, r = l & 15;

  const bf16* kbase = kp + (size_t)(b * T_) * E_ + h * D_;
  const bf16* vbase = vt + (size_t)bh * D_ * T_;
  bf16* pw = sP + w * (16 * PSTR);

  // staging coords: chunk i -> idx=i*256+tid, row=idx>>3, cc=(idx&7)*8
  int srow[2], scc[2];
#pragma unroll
  for (int i = 0; i < 2; ++i) {
    int idx = i * 256 + tid;
    srow[i] = idx >> 3;
    scc[i] = (idx & 7) * 8;
  }

#pragma unroll 1
  for (int s = 0; s < 2; ++s) {
    int qt = s ? (31 - pairIdx) : pairIdx;
    int Q0 = qt * 64;

    int qrow = Q0 + w * 16 + r;
    const bf16* qbase = qp + (size_t)(b * T_ + qrow) * E_ + h * D_;
    bf16x8 qa0 = *(const bf16x8*)(qbase + q * 8);
    bf16x8 qa1 = *(const bf16x8*)(qbase + 32 + q * 8);

    float m_i[4], l_i[4];
    floatx4 o_acc[4];
#pragma unroll
    for (int i = 0; i < 4; ++i) {
      m_i[i] = NEG_BIG;
      l_i[i] = 0.f;
      o_acc[i] = (floatx4){0.f, 0.f, 0.f, 0.f};
    }

    // prefetch tile 0 into registers
    bf16x8 kreg[2], vreg[2];
#pragma unroll
    for (int i = 0; i < 2; ++i) {
      kreg[i] = *(const bf16x8*)(kbase + (size_t)srow[i] * E_ + scc[i]);
      vreg[i] = *(const bf16x8*)(vbase + (size_t)srow[i] * T_ + scc[i]);
    }

    for (int kt0 = 0; kt0 <= Q0; kt0 += 64) {
      __syncthreads();  // prior iter's LDS reads complete
#pragma unroll
      for (int i = 0; i < 2; ++i) {
        *(bf16x8*)(sK + srow[i] * KSTR + scc[i]) = kreg[i];
        *(bf16x8*)(sV + srow[i] * KSTR + scc[i]) = vreg[i];
      }
      if (kt0 + 64 <= Q0) {
        int kt1 = kt0 + 64;
#pragma unroll
        for (int i = 0; i < 2; ++i) {
          kreg[i] = *(const bf16x8*)(kbase + (size_t)(kt1 + srow[i]) * E_ + scc[i]);
          vreg[i] = *(const bf16x8*)(vbase + (size_t)srow[i] * T_ + kt1 + scc[i]);
        }
      }
      __syncthreads();  // staged tile visible

      // S = Q K^T
      floatx4 sreg[4];
#pragma unroll
      for (int sc = 0; sc < 4; ++sc) {
        bf16x8 kb0 = *(const bf16x8*)(sK + (sc * 16 + r) * KSTR + q * 8);
        bf16x8 kb1 = *(const bf16x8*)(sK + (sc * 16 + r) * KSTR + 32 + q * 8);
        floatx4 a = (floatx4){0.f, 0.f, 0.f, 0.f};
        a = mfma16(qa0, kb0, a);
        a = mfma16(qa1, kb1, a);
        sreg[sc] = a;
      }

      // scale (+ mask only on the diagonal tile) + row max
      float rowmax[4] = {NEG_BIG, NEG_BIG, NEG_BIG, NEG_BIG};
      if (kt0 == Q0) {
#pragma unroll
        for (int sc = 0; sc < 4; ++sc) {
          int kglob = kt0 + sc * 16 + r;
#pragma unroll
          for (int rr = 0; rr < 4; ++rr) {
            int qglob = Q0 + w * 16 + q * 4 + rr;
            float v = sreg[sc][rr] * 0.125f;
            v = (kglob <= qglob) ? v : NEG_BIG;
            sreg[sc][rr] = v;
            rowmax[rr] = fmaxf(rowmax[rr], v);
          }
        }
      } else {
#pragma unroll
        for (int sc = 0; sc < 4; ++sc)
#pragma unroll
          for (int rr = 0; rr < 4; ++rr) {
            float v = sreg[sc][rr] * 0.125f;
            sreg[sc][rr] = v;
            rowmax[rr] = fmaxf(rowmax[rr], v);
          }
      }
#pragma unroll
      for (int rr = 0; rr < 4; ++rr)
#pragma unroll
        for (int m = 1; m < 16; m <<= 1)
          rowmax[rr] = fmaxf(rowmax[rr], __shfl_xor(rowmax[rr], m, 64));

      float alpha[4];
#pragma unroll
      for (int rr = 0; rr < 4; ++rr) {
        float mnew = fmaxf(m_i[rr], rowmax[rr]);
        alpha[rr] = __expf(m_i[rr] - mnew);
        m_i[rr] = mnew;
      }

      float rowsum[4] = {0.f, 0.f, 0.f, 0.f};
#pragma unroll
      for (int sc = 0; sc < 4; ++sc)
#pragma unroll
        for (int rr = 0; rr < 4; ++rr) {
          float p = __expf(sreg[sc][rr] - m_i[rr]);
          sreg[sc][rr] = p;
          rowsum[rr] += p;
        }
#pragma unroll
      for (int rr = 0; rr < 4; ++rr)
#pragma unroll
        for (int m = 1; m < 16; m <<= 1) rowsum[rr] += __shfl_xor(rowsum[rr], m, 64);
#pragma unroll
      for (int rr = 0; rr < 4; ++rr) l_i[rr] = l_i[rr] * alpha[rr] + rowsum[rr];

      // P: C-layout -> wave-private LDS (row-major [q_local][key])
#pragma unroll
      for (int sc = 0; sc < 4; ++sc)
#pragma unroll
        for (int rr = 0; rr < 4; ++rr)
          pw[(q * 4 + rr) * PSTR + sc * 16 + r] = (bf16)sreg[sc][rr];
      asm volatile("s_waitcnt lgkmcnt(0)" ::: "memory");

#pragma unroll
      for (int dt = 0; dt < 4; ++dt)
#pragma unroll
        for (int rr = 0; rr < 4; ++rr) o_acc[dt][rr] *= alpha[rr];

      // O += P V
#pragma unroll
      for (int kk = 0; kk < 2; ++kk) {
        bf16x8 pa = *(const bf16x8*)(pw + r * PSTR + kk * 32 + q * 8);
#pragma unroll
        for (int dt = 0; dt < 4; ++dt) {
          bf16x8 vb = *(const bf16x8*)(sV + (dt * 16 + r) * KSTR + kk * 32 + q * 8);
          o_acc[dt] = mfma16(pa, vb, o_acc[dt]);
        }
      }
    }

    // epilogue for this strip
#pragma unroll
    for (int dt = 0; dt < 4; ++dt)
#pragma unroll
      for (int rr = 0; rr < 4; ++rr) {
        int t = Q0 + w * 16 + q * 4 + rr;
        float oo = o_acc[dt][rr] / l_i[rr];  // l_i >= 1 (diagonal term)
        op[(size_t)(b * T_ + t) * E_ + h * D_ + dt * 16 + r] = (bf16)oo;
      }
  }
}

// ---------------------------------------------------------------------------
extern "C" void kernel_launch(void* const* d_in, const int* in_sizes, int n_in,
                              void* d_out, int out_size, void* d_ws, size_t ws_size,
                              hipStream_t stream) {
  float* out = (float*)d_out;  // fp32 output, per reference

  void* cvp_ = nullptr;
  void* sp_ = nullptr;
  hipGetSymbolAddress(&cvp_, HIP_SYMBOL(g_conv));
  hipGetSymbolAddress(&sp_, HIP_SYMBOL(g_scratch));
  bf16* cv = (bf16*)cvp_;
  bf16* sc = (bf16*)sp_;

  const float* cosb = (const float*)d_in[4];
  const float* sinb = (const float*)d_in[5];
  const float* bq = (const float*)d_in[7];
  const float* bk = (const float*)d_in[9];
  const float* bv = (const float*)d_in[11];
  const float* bo = (const float*)d_in[13];

  convert_all<<<dim3(1024), dim3(256), 0, stream>>>(
      (const float4*)d_in[0], (const float4*)d_in[1], (const float4*)d_in[2],
      (const float4*)d_in[6], (const float4*)d_in[8], (const float4*)d_in[10],
      (const float4*)d_in[12]);

  bf16* qp = sc;
  bf16* kp = sc + 1ull * NTE_;
  bf16* vp = sc + 2ull * NTE_;
  bf16* op = sc + 4ull * NTE_;

  dim3 gg(64, 8), bb(256);
  gemm_bt<bf16><<<gg, bb, 0, stream>>>(cv + OFF_CQ, cv + OFF_WQ, bq, qp);
  gemm_bt<bf16><<<gg, bb, 0, stream>>>(cv + OFF_CK, cv + OFF_WK, bk, kp);
  gemm_bt<bf16><<<gg, bb, 0, stream>>>(cv + OFF_CV, cv + OFF_WV, bv, vp);
  rmsnorm_rope<<<dim3(16384), bb, 0, stream>>>(cosb, sinb);
  transpose_v<<<dim3(2048), bb, 0, stream>>>();
  flash_attn<<<dim3(1024), bb, 0, stream>>>();
  gemm_bt<float><<<gg, bb, 0, stream>>>(op, cv + OFF_WO, bo, out);
}

// Round 8
// 425.157 us; speedup vs baseline: 1.8575x; 1.1369x over previous
//
#include <hip/hip_runtime.h>

typedef __bf16 bf16;
typedef __bf16 bf16x8 __attribute__((ext_vector_type(8)));
typedef __bf16 bf16x4 __attribute__((ext_vector_type(4)));
typedef float  floatx4 __attribute__((ext_vector_type(4)));

#define B_ 4
#define T_ 2048
#define E_ 1024
#define H_ 16
#define D_ 64
#define NTE_ (B_ * T_ * E_)  // 8388608 elems

#define NEG_BIG (-1e30f)
#define SMAX 8.5f  // static softmax max: |q.k|/8 <= 8 (RMS norm => |q|=|k|=8; RoPE is a rotation)

// ---- static device memory ------------------------------------------------
#define OFF_CQ 0ull
#define OFF_CK ((unsigned long long)NTE_)
#define OFF_CV (2ull * NTE_)
#define OFF_WQ (3ull * NTE_)
#define OFF_WK (OFF_WQ + 1048576ull)
#define OFF_WV (OFF_WK + 1048576ull)
#define OFF_WO (OFF_WV + 1048576ull)
__device__ bf16 g_conv[3ull * NTE_ + 4ull * 1048576ull];
// Pipeline scratch: qp | kp | vp | vt | op
__device__ bf16 g_scratch[5ull * NTE_];

__device__ __forceinline__ floatx4 mfma16(bf16x8 a, bf16x8 b, floatx4 c) {
  return __builtin_amdgcn_mfma_f32_16x16x32_bf16(a, b, c, 0, 0, 0);
}

__device__ __forceinline__ void async_copy16(void* lds, const void* g) {
  __builtin_amdgcn_global_load_lds(
      (const __attribute__((address_space(1))) unsigned int*)g,
      (__attribute__((address_space(3))) unsigned int*)lds, 16, 0, 0);
}

// ---------------------------------------------------------------------------
// One fused fp32->bf16 convert for the 7 MFMA-feeding tensors.
// ---------------------------------------------------------------------------
__global__ __launch_bounds__(256) void convert_all(const float4* __restrict__ q,
                                                   const float4* __restrict__ k,
                                                   const float4* __restrict__ v,
                                                   const float4* __restrict__ wq,
                                                   const float4* __restrict__ wk,
                                                   const float4* __restrict__ wv,
                                                   const float4* __restrict__ wo) {
  const float4* srcs[7] = {q, k, v, wq, wk, wv, wo};
  bf16x4* dsts[7] = {(bf16x4*)(g_conv + OFF_CQ), (bf16x4*)(g_conv + OFF_CK),
                     (bf16x4*)(g_conv + OFF_CV), (bf16x4*)(g_conv + OFF_WQ),
                     (bf16x4*)(g_conv + OFF_WK), (bf16x4*)(g_conv + OFF_WV),
                     (bf16x4*)(g_conv + OFF_WO)};
  const int n4s[7] = {NTE_ / 4, NTE_ / 4, NTE_ / 4, 262144, 262144, 262144, 262144};
  int i0 = blockIdx.x * 256 + threadIdx.x;
  int stride = gridDim.x * 256;
#pragma unroll
  for (int s = 0; s < 7; ++s) {
    const float4* sp = srcs[s];
    bf16x4* dp = dsts[s];
    int n4 = n4s[s];
    for (int i = i0; i < n4; i += stride) {
      float4 vv = sp[i];
      bf16x4 o;
      o[0] = (bf16)vv.x; o[1] = (bf16)vv.y; o[2] = (bf16)vv.z; o[3] = (bf16)vv.w;
      dp[i] = o;
    }
  }
}

// ---------------------------------------------------------------------------
// Batched projection GEMM: z in [0,3) selects {q,k,v} x {Wq,Wk,Wv} -> qp/kp/vp.
// (CQ/CK/CV, WQ/WK/WV, and scratch outputs are contiguous.)
// 128x128 tile, 4 waves, BK=32, global_load_lds width-16 staging.
// ---------------------------------------------------------------------------
__global__ __launch_bounds__(256) void gemm_qkv(const float* __restrict__ bq,
                                                const float* __restrict__ bk,
                                                const float* __restrict__ bv) {
  constexpr int K = 1024, N = 1024;
  const int z = blockIdx.z;
  const bf16* X = g_conv + OFF_CQ + (unsigned long long)z * NTE_;
  const bf16* W = g_conv + OFF_WQ + (unsigned long long)z * 1048576ull;
  const float* bias = (z == 0) ? bq : (z == 1) ? bk : bv;
  bf16* Y = g_scratch + (unsigned long long)z * NTE_;

  __shared__ bf16 sA[128 * 32];
  __shared__ bf16 sB[128 * 32];
  const int tid = threadIdx.x;
  const int w = tid >> 6;
  const int l = tid & 63;
  const int q = l >> 4;
  const int r = l & 15;
  const int M0 = blockIdx.x * 128;
  const int N0 = blockIdx.y * 128;
  const int wm = (w >> 1) * 64, wn = (w & 1) * 64;

  floatx4 acc[4][4];
  for (int mi = 0; mi < 4; ++mi)
    for (int ni = 0; ni < 4; ++ni) acc[mi][ni] = (floatx4){0.f, 0.f, 0.f, 0.f};

  for (int k0 = 0; k0 < K; k0 += 32) {
    __syncthreads();
#pragma unroll
    for (int i = 0; i < 2; ++i) {
      int idx = i * 256 + tid;
      int row = idx >> 2, cc = (idx & 3) << 3;
      bf16* dA = sA + (i * 2048 + w * 512);
      async_copy16(dA, X + (size_t)(M0 + row) * K + k0 + cc);
      bf16* dB = sB + (i * 2048 + w * 512);
      async_copy16(dB, W + (size_t)(N0 + row) * K + k0 + cc);
    }
    __syncthreads();

    bf16x8 a[4], b[4];
#pragma unroll
    for (int mi = 0; mi < 4; ++mi)
      a[mi] = *(const bf16x8*)(sA + (wm + mi * 16 + r) * 32 + q * 8);
#pragma unroll
    for (int ni = 0; ni < 4; ++ni)
      b[ni] = *(const bf16x8*)(sB + (wn + ni * 16 + r) * 32 + q * 8);
#pragma unroll
    for (int mi = 0; mi < 4; ++mi)
#pragma unroll
      for (int ni = 0; ni < 4; ++ni) acc[mi][ni] = mfma16(a[mi], b[ni], acc[mi][ni]);
  }

#pragma unroll
  for (int mi = 0; mi < 4; ++mi) {
    int rowbase = M0 + wm + mi * 16 + q * 4;
#pragma unroll
    for (int ni = 0; ni < 4; ++ni) {
      int col = N0 + wn + ni * 16 + r;
      float bv_ = bias[col];
#pragma unroll
      for (int rr = 0; rr < 4; ++rr) {
        Y[(size_t)(rowbase + rr) * N + col] = (bf16)(acc[mi][ni][rr] + bv_);
      }
    }
  }
}

// ---------------------------------------------------------------------------
// Final projection GEMM (fp32 out).
// ---------------------------------------------------------------------------
__global__ __launch_bounds__(256) void gemm_out(const bf16* __restrict__ X,
                                                const bf16* __restrict__ W,
                                                const float* __restrict__ bias,
                                                float* __restrict__ Y) {
  constexpr int K = 1024, N = 1024;
  __shared__ bf16 sA[128 * 32];
  __shared__ bf16 sB[128 * 32];
  const int tid = threadIdx.x;
  const int w = tid >> 6;
  const int l = tid & 63;
  const int q = l >> 4;
  const int r = l & 15;
  const int M0 = blockIdx.x * 128;
  const int N0 = blockIdx.y * 128;
  const int wm = (w >> 1) * 64, wn = (w & 1) * 64;

  floatx4 acc[4][4];
  for (int mi = 0; mi < 4; ++mi)
    for (int ni = 0; ni < 4; ++ni) acc[mi][ni] = (floatx4){0.f, 0.f, 0.f, 0.f};

  for (int k0 = 0; k0 < K; k0 += 32) {
    __syncthreads();
#pragma unroll
    for (int i = 0; i < 2; ++i) {
      int idx = i * 256 + tid;
      int row = idx >> 2, cc = (idx & 3) << 3;
      bf16* dA = sA + (i * 2048 + w * 512);
      async_copy16(dA, X + (size_t)(M0 + row) * K + k0 + cc);
      bf16* dB = sB + (i * 2048 + w * 512);
      async_copy16(dB, W + (size_t)(N0 + row) * K + k0 + cc);
    }
    __syncthreads();

    bf16x8 a[4], b[4];
#pragma unroll
    for (int mi = 0; mi < 4; ++mi)
      a[mi] = *(const bf16x8*)(sA + (wm + mi * 16 + r) * 32 + q * 8);
#pragma unroll
    for (int ni = 0; ni < 4; ++ni)
      b[ni] = *(const bf16x8*)(sB + (wn + ni * 16 + r) * 32 + q * 8);
#pragma unroll
    for (int mi = 0; mi < 4; ++mi)
#pragma unroll
      for (int ni = 0; ni < 4; ++ni) acc[mi][ni] = mfma16(a[mi], b[ni], acc[mi][ni]);
  }

#pragma unroll
  for (int mi = 0; mi < 4; ++mi) {
    int rowbase = M0 + wm + mi * 16 + q * 4;
#pragma unroll
    for (int ni = 0; ni < 4; ++ni) {
      int col = N0 + wn + ni * 16 + r;
      float bv = bias[col];
#pragma unroll
      for (int rr = 0; rr < 4; ++rr) {
        Y[(size_t)(rowbase + rr) * N + col] = acc[mi][ni][rr] + bv;
      }
    }
  }
}

// ---------------------------------------------------------------------------
// RMSNorm + RoPE in place on qp,kp; q additionally pre-scaled by 1/sqrt(D)=0.125
// so flash_attn needs no per-score scaling.
// ---------------------------------------------------------------------------
__global__ __launch_bounds__(256) void rmsnorm_rope(const float* __restrict__ cosb,
                                                    const float* __restrict__ sinb) {
  bf16* qp = g_scratch;
  bf16* kp = g_scratch + (unsigned long long)NTE_;
  constexpr int HR = B_ * T_ * H_;
  int gid = blockIdx.x * 16 + (threadIdx.x >> 4);
  int j = threadIdx.x & 15;
  bool isq = (gid < HR);
  bf16* base = isq ? qp : kp;
  float post = isq ? 0.125f : 1.0f;
  int row = gid & (HR - 1);
  int t = (row >> 4) & (T_ - 1);
  bf16* p = base + (size_t)row * 64 + j * 4;

  bf16x4 xv = *(const bf16x4*)p;
  float x[4], ss = 0.f;
#pragma unroll
  for (int i = 0; i < 4; ++i) { x[i] = (float)xv[i]; ss += x[i] * x[i]; }
#pragma unroll
  for (int m = 1; m < 16; m <<= 1) ss += __shfl_xor(ss, m, 64);
  float rs = rsqrtf(ss * (1.0f / 64.0f) + 1e-6f);

  float y[4], pr[4];
#pragma unroll
  for (int i = 0; i < 4; ++i) y[i] = x[i] * rs;
#pragma unroll
  for (int i = 0; i < 4; ++i) pr[i] = __shfl_xor(y[i], 8, 64);

  int dbase = (j & 7) * 4;
  bf16x4 ov;
#pragma unroll
  for (int i = 0; i < 4; ++i) {
    float c = cosb[t * 32 + dbase + i];
    float s = sinb[t * 32 + dbase + i];
    float o = (j < 8) ? (y[i] * c - pr[i] * s) : (y[i] * c + pr[i] * s);
    ov[i] = (bf16)(o * post);
  }
  *(bf16x4*)p = ov;
}

// ---------------------------------------------------------------------------
// Transpose V: vp (b,t,h,d) -> vt (b,h,d,t).
// ---------------------------------------------------------------------------
__global__ __launch_bounds__(256) void transpose_v() {
  const bf16* vp = g_scratch + 2ull * NTE_;
  bf16* vt = g_scratch + 3ull * NTE_;
  __shared__ bf16 tile[64][72];
  int bid = blockIdx.x;
  int tt = bid & 31;
  int bh = bid >> 5;
  int h = bh & 15, b = bh >> 4;
  int t0 = tt * 64;
  int tid = threadIdx.x;
#pragma unroll
  for (int i = 0; i < 2; ++i) {
    int idx = i * 256 + tid;
    int row = idx >> 3, cc = (idx & 7) * 8;
    bf16x8 v = *(const bf16x8*)(vp + (size_t)(b * T_ + t0 + row) * E_ + h * D_ + cc);
#pragma unroll
    for (int jj = 0; jj < 8; ++jj) tile[row][cc + jj] = v[jj];
  }
  __syncthreads();
#pragma unroll
  for (int i = 0; i < 2; ++i) {
    int idx = i * 256 + tid;
    int d = idx >> 3, tc = (idx & 7) * 8;
    bf16x8 v;
#pragma unroll
    for (int jj = 0; jj < 8; ++jj) v[jj] = tile[tc + jj][d];
    *(bf16x8*)(vt + ((size_t)bh * D_ + d) * T_ + t0 + tc) = v;
  }
}

// ---------------------------------------------------------------------------
// Flash attention, causal, STATIC-MAX softmax.
// Scores s = q'.k with q' pre-scaled => s <= 8 provably; use M=8.5, so
// p = exp(s - M) needs NO running max, NO alpha rescale, NO shuffle
// reductions. Row-sum l accumulated by 2 extra MFMAs with all-ones B
// (C-layout broadcasts rowsum across col lanes, matching o_acc indexing).
// LDS-staged K/V, register double-buffer, padded strides, paired strips.
// ---------------------------------------------------------------------------
#define KSTR 72
#define PSTR 68
__global__ __launch_bounds__(256) void flash_attn() {
  const bf16* qp = g_scratch;
  const bf16* kp = g_scratch + (unsigned long long)NTE_;
  const bf16* vt = g_scratch + 3ull * NTE_;
  bf16* op = g_scratch + 4ull * NTE_;

  __shared__ bf16 sK[64 * KSTR];
  __shared__ bf16 sV[64 * KSTR];     // [d][key]
  __shared__ bf16 sP[4 * 16 * PSTR]; // wave-private strips

  int bid = blockIdx.x;
  int pairIdx = bid & 15;
  int bh = bid >> 4;
  int h = bh & 15, b = bh >> 4;
  int tid = threadIdx.x, w = tid >> 6, l = tid & 63, q = l >> 4, r = l & 15;

  const bf16* kbase = kp + (size_t)(b * T_) * E_ + h * D_;
  const bf16* vbase = vt + (size_t)bh * D_ * T_;
  bf16* pw = sP + w * (16 * PSTR);

  bf16x8 ones;
#pragma unroll
  for (int i = 0; i < 8; ++i) ones[i] = (bf16)1.0f;

  int srow[2], scc[2];
#pragma unroll
  for (int i = 0; i < 2; ++i) {
    int idx = i * 256 + tid;
    srow[i] = idx >> 3;
    scc[i] = (idx & 7) * 8;
  }

#pragma unroll 1
  for (int s = 0; s < 2; ++s) {
    int qt = s ? (31 - pairIdx) : pairIdx;
    int Q0 = qt * 64;

    int qrow = Q0 + w * 16 + r;
    const bf16* qbase = qp + (size_t)(b * T_ + qrow) * E_ + h * D_;
    bf16x8 qa0 = *(const bf16x8*)(qbase + q * 8);
    bf16x8 qa1 = *(const bf16x8*)(qbase + 32 + q * 8);

    floatx4 o_acc[4];
    floatx4 l_acc = (floatx4){0.f, 0.f, 0.f, 0.f};
#pragma unroll
    for (int i = 0; i < 4; ++i) o_acc[i] = (floatx4){0.f, 0.f, 0.f, 0.f};

    // prefetch tile 0 into registers
    bf16x8 kreg[2], vreg[2];
#pragma unroll
    for (int i = 0; i < 2; ++i) {
      kreg[i] = *(const bf16x8*)(kbase + (size_t)srow[i] * E_ + scc[i]);
      vreg[i] = *(const bf16x8*)(vbase + (size_t)srow[i] * T_ + scc[i]);
    }

    for (int kt0 = 0; kt0 <= Q0; kt0 += 64) {
      __syncthreads();
#pragma unroll
      for (int i = 0; i < 2; ++i) {
        *(bf16x8*)(sK + srow[i] * KSTR + scc[i]) = kreg[i];
        *(bf16x8*)(sV + srow[i] * KSTR + scc[i]) = vreg[i];
      }
      if (kt0 + 64 <= Q0) {
        int kt1 = kt0 + 64;
#pragma unroll
        for (int i = 0; i < 2; ++i) {
          kreg[i] = *(const bf16x8*)(kbase + (size_t)(kt1 + srow[i]) * E_ + scc[i]);
          vreg[i] = *(const bf16x8*)(vbase + (size_t)srow[i] * T_ + kt1 + scc[i]);
        }
      }
      __syncthreads();

      // S = Q K^T  (q pre-scaled; s <= 8 by construction)
      floatx4 sreg[4];
#pragma unroll
      for (int sc = 0; sc < 4; ++sc) {
        bf16x8 kb0 = *(const bf16x8*)(sK + (sc * 16 + r) * KSTR + q * 8);
        bf16x8 kb1 = *(const bf16x8*)(sK + (sc * 16 + r) * KSTR + 32 + q * 8);
        floatx4 a = (floatx4){0.f, 0.f, 0.f, 0.f};
        a = mfma16(qa0, kb0, a);
        a = mfma16(qa1, kb1, a);
        sreg[sc] = a;
      }

      // diagonal-tile causal mask
      if (kt0 == Q0) {
#pragma unroll
        for (int sc = 0; sc < 4; ++sc) {
          int kglob = kt0 + sc * 16 + r;
#pragma unroll
          for (int rr = 0; rr < 4; ++rr) {
            int qglob = Q0 + w * 16 + q * 4 + rr;
            sreg[sc][rr] = (kglob <= qglob) ? sreg[sc][rr] : NEG_BIG;
          }
        }
      }

      // p = exp(s - SMAX), straight to LDS (C-layout -> row-major strip)
#pragma unroll
      for (int sc = 0; sc < 4; ++sc)
#pragma unroll
        for (int rr = 0; rr < 4; ++rr)
          pw[(q * 4 + rr) * PSTR + sc * 16 + r] = (bf16)__expf(sreg[sc][rr] - SMAX);
      asm volatile("s_waitcnt lgkmcnt(0)" ::: "memory");

      // O += P V ; l += P . 1
#pragma unroll
      for (int kk = 0; kk < 2; ++kk) {
        bf16x8 pa = *(const bf16x8*)(pw + r * PSTR + kk * 32 + q * 8);
        l_acc = mfma16(pa, ones, l_acc);
#pragma unroll
        for (int dt = 0; dt < 4; ++dt) {
          bf16x8 vb = *(const bf16x8*)(sV + (dt * 16 + r) * KSTR + kk * 32 + q * 8);
          o_acc[dt] = mfma16(pa, vb, o_acc[dt]);
        }
      }
    }

    // epilogue: O /= l  (l >= exp(diag - SMAX) > 0)
#pragma unroll
    for (int rr = 0; rr < 4; ++rr) l_acc[rr] = 1.0f / l_acc[rr];
#pragma unroll
    for (int dt = 0; dt < 4; ++dt)
#pragma unroll
      for (int rr = 0; rr < 4; ++rr) {
        int t = Q0 + w * 16 + q * 4 + rr;
        op[(size_t)(b * T_ + t) * E_ + h * D_ + dt * 16 + r] =
            (bf16)(o_acc[dt][rr] * l_acc[rr]);
      }
  }
}

// ---------------------------------------------------------------------------
extern "C" void kernel_launch(void* const* d_in, const int* in_sizes, int n_in,
                              void* d_out, int out_size, void* d_ws, size_t ws_size,
                              hipStream_t stream) {
  float* out = (float*)d_out;  // fp32 output, per reference

  void* cvp_ = nullptr;
  void* sp_ = nullptr;
  hipGetSymbolAddress(&cvp_, HIP_SYMBOL(g_conv));
  hipGetSymbolAddress(&sp_, HIP_SYMBOL(g_scratch));
  bf16* cv = (bf16*)cvp_;
  bf16* sc = (bf16*)sp_;

  const float* cosb = (const float*)d_in[4];
  const float* sinb = (const float*)d_in[5];
  const float* bq = (const float*)d_in[7];
  const float* bk = (const float*)d_in[9];
  const float* bv = (const float*)d_in[11];
  const float* bo = (const float*)d_in[13];

  convert_all<<<dim3(1024), dim3(256), 0, stream>>>(
      (const float4*)d_in[0], (const float4*)d_in[1], (const float4*)d_in[2],
      (const float4*)d_in[6], (const float4*)d_in[8], (const float4*)d_in[10],
      (const float4*)d_in[12]);

  bf16* op = sc + 4ull * NTE_;

  dim3 bb(256);
  gemm_qkv<<<dim3(64, 8, 3), bb, 0, stream>>>(bq, bk, bv);
  rmsnorm_rope<<<dim3(16384), bb, 0, stream>>>(cosb, sinb);
  transpose_v<<<dim3(2048), bb, 0, stream>>>();
  flash_attn<<<dim3(1024), bb, 0, stream>>>();
  gemm_out<<<dim3(64, 8), bb, 0, stream>>>(op, cv + OFF_WO, bo, out);
}